// Round 1
// baseline (334.025 us; speedup 1.0000x reference)
//
#include <hip/hip_runtime.h>
#include <math.h>

#define NQ 10
#define DIM 1024
#define NL 3
#define PI_F 3.14159265358979f
#define EPB 4          // batch elements per block
#define TPB 128        // 32 threads per batch element
#define SLOTS 1056     // 1024 + 32 pad words (1 per 32) -> conflict-free transpose

// Composed CNOT-ring permutation: P(k) = perms[0][perms[1][...perms[9][k]]]
// (reference applies state = state[:, perms[i]] for i = 0..9, so innermost is perms[9]).
// Each CNOT is a conditional XOR -> P is GF(2)-linear: P(a^b) = P(a)^P(b), P(0)=0.
__device__ __host__ __forceinline__ int cnot_chain(int j) {
#pragma unroll
    for (int i = NQ - 1; i >= 0; --i) {
        int tq = (i + 1) % NQ;
        j ^= ((j >> (NQ - 1 - i)) & 1) << (NQ - 1 - tq);
    }
    return j;
}

// one 2x2 complex gate on register state; pb = in-register bit position.
// pb / loop indices are compile-time after unroll -> ar/ai stay in VGPRs.
#define APPLY_GATE(pb, m0, m1)                                                \
    {                                                                         \
        _Pragma("unroll")                                                     \
        for (int j0 = 0; j0 < 32; ++j0) {                                     \
            if (((j0 >> (pb)) & 1) == 0) {                                    \
                const int j1 = j0 | (1 << (pb));                              \
                float s0r = ar[j0], s0i = ai[j0];                             \
                float s1r = ar[j1], s1i = ai[j1];                             \
                ar[j0] = m0.x * s0r - m0.y * s0i + m0.z * s1r - m0.w * s1i;   \
                ai[j0] = m0.x * s0i + m0.y * s0r + m0.z * s1i + m0.w * s1r;   \
                ar[j1] = m1.x * s0r - m1.y * s0i + m1.z * s1r - m1.w * s1i;   \
                ai[j1] = m1.x * s0i + m1.y * s0r + m1.z * s1i + m1.w * s1r;   \
            }                                                                 \
        }                                                                     \
    }

__global__ __launch_bounds__(TPB, 2) void vq_main(
        const float* __restrict__ x, const float* __restrict__ w,
        float* __restrict__ out) {
    __shared__ float sre[EPB][SLOTS];
    __shared__ float sim[EPB][SLOTS];
    __shared__ float4 msh[NL * NQ * 2];   // 30 fused gate matrices, 2 float4 each

    const int tid = threadIdx.x;
    const int e = tid >> 5;        // batch sub-element in block
    const int t = tid & 31;        // thread within batch element
    const int b = blockIdx.x * EPB + e;

    // ---- per-block: fused M = Rz(c) * Ry(b) * Rx(a), one complex 2x2 per (layer,qubit)
    if (tid < NL * NQ) {
        const float* wp = w + tid * 3;
        float sa, ca, sb, cb, sc, cc;
        sincosf(wp[0] * 0.5f, &sa, &ca);
        sincosf(wp[1] * 0.5f, &sb, &cb);
        sincosf(wp[2] * 0.5f, &sc, &cc);
        // C = Ry*Rx
        float c00r = cb * ca,  c00i =  sa * sb;
        float c01r = -sb * ca, c01i = -cb * sa;
        float c10r =  sb * ca, c10i = -cb * sa;
        float c11r =  cb * ca, c11i = -sb * sa;
        // M = Rz*C : row0 *= (cc - i sc), row1 *= (cc + i sc)
        float4 m0, m1;
        m0.x = cc * c00r + sc * c00i;  m0.y = cc * c00i - sc * c00r;
        m0.z = cc * c01r + sc * c01i;  m0.w = cc * c01i - sc * c01r;
        m1.x = cc * c10r - sc * c10i;  m1.y = cc * c10i + sc * c10r;
        m1.z = cc * c11r - sc * c11i;  m1.w = cc * c11i + sc * c11r;
        msh[tid * 2] = m0;
        msh[tid * 2 + 1] = m1;
    }

    // ---- encoding half-angles: h = tanh(x)*pi/2
    float cq[NQ], sq[NQ];
#pragma unroll
    for (int q = 0; q < NQ; ++q) {
        float h = tanhf(x[b * NQ + q]) * (PI_F * 0.5f);
        sincosf(h, &sq[q], &cq[q]);
    }

    // P(t<<5) via GF(2) linearity (cnot_chain of constants folds at compile time)
    int Pt = 0;
#pragma unroll
    for (int m = 0; m < 5; ++m)
        Pt ^= ((t >> m) & 1) ? cnot_chain(1 << (5 + m)) : 0;

    __syncthreads();   // msh ready

    float ar[32], ai[32];   // register state, phase A: k = t*32 + j

    // ---- layer 0 phase A: product-state amplitude evaluated at P(k) (perm fused)
#pragma unroll
    for (int j = 0; j < 32; ++j) {
        const int pj = cnot_chain(j);      // compile-time constant
        int pk = Pt ^ pj;
        float r = 1.0f;
#pragma unroll
        for (int q = 0; q < NQ; ++q)
            r *= ((pk >> (9 - q)) & 1) ? sq[q] : cq[q];
        ar[j] = r;
        ai[j] = 0.0f;
    }

#pragma unroll 1
    for (int l = 0; l < NL; ++l) {
        if (l > 0) {
            // phase A gather with CNOT-ring perm fused: s_new(k) = s_old(P(k))
#pragma unroll
            for (int j = 0; j < 32; ++j) {
                const int pj = cnot_chain(j);
                int pk = Pt ^ pj;
                int slot = pk + (pk >> 5);
                ar[j] = sre[e][slot];
                ai[j] = sim[e][slot];
            }
            __syncthreads();   // all reads done before anyone overwrites
        }
        // phase A gates: qubits 5..9 (k-bit 9-q == j-bit)
#pragma unroll
        for (int q = 5; q < NQ; ++q) {
            float4 m0 = msh[(l * NQ + q) * 2];
            float4 m1 = msh[(l * NQ + q) * 2 + 1];
            APPLY_GATE(9 - q, m0, m1);
        }
        // write phase-A layout: amp(t*32+j) -> slot t*33+j  (bank (t+j)%32: free)
#pragma unroll
        for (int j = 0; j < 32; ++j) {
            sre[e][t * 33 + j] = ar[j];
            sim[e][t * 33 + j] = ai[j];
        }
        __syncthreads();
        // phase B read: k = j*32 + t -> slot j*33+t (bank (j+t)%32: free)
#pragma unroll
        for (int j = 0; j < 32; ++j) {
            ar[j] = sre[e][j * 33 + t];
            ai[j] = sim[e][j * 33 + t];
        }
        // phase B gates: qubits 0..4 (k-bit 9-q == j-bit 4-q)
#pragma unroll
        for (int q = 0; q < 5; ++q) {
            float4 m0 = msh[(l * NQ + q) * 2];
            float4 m1 = msh[(l * NQ + q) * 2 + 1];
            APPLY_GATE(4 - q, m0, m1);
        }
        if (l < NL - 1) {
            // same slots this thread just read -> no barrier needed before writes
#pragma unroll
            for (int j = 0; j < 32; ++j) {
                sre[e][j * 33 + t] = ar[j];
                sim[e][j * 33 + t] = ai[j];
            }
            __syncthreads();
        }
    }

    // ---- readout directly from phase-B registers: k = j*32 + t
    // out[b,w] = sum_k (1 - 2*bit_{9-w}(k)) * |s_k|^2
    float accw[NQ];
    float S = 0.0f;
#pragma unroll
    for (int wi = 0; wi < 5; ++wi) accw[wi] = 0.0f;
#pragma unroll
    for (int j = 0; j < 32; ++j) {
        float p = ar[j] * ar[j] + ai[j] * ai[j];
        S += p;
#pragma unroll
        for (int wi = 0; wi < 5; ++wi)           // qubits 0..4 live in j bits
            accw[wi] += ((j >> (4 - wi)) & 1) ? -p : p;
    }
#pragma unroll
    for (int wi = 5; wi < NQ; ++wi)              // qubits 5..9 live in t bits
        accw[wi] = ((t >> (9 - wi)) & 1) ? -S : S;

    // reduce across the 32 threads of this batch element (stays in half-wave)
#pragma unroll
    for (int wi = 0; wi < NQ; ++wi) {
        float v = accw[wi];
        v += __shfl_xor(v, 16);
        v += __shfl_xor(v, 8);
        v += __shfl_xor(v, 4);
        v += __shfl_xor(v, 2);
        v += __shfl_xor(v, 1);
        accw[wi] = v;
    }
    if (t == 0) {
#pragma unroll
        for (int wi = 0; wi < NQ; ++wi)
            out[b * NQ + wi] = accw[wi];
    }
}

extern "C" void kernel_launch(void* const* d_in, const int* in_sizes, int n_in,
                              void* d_out, int out_size, void* d_ws, size_t ws_size,
                              hipStream_t stream) {
    const float* x = (const float*)d_in[0];   // (16384, 10) fp32
    const float* w = (const float*)d_in[1];   // (3, 10, 3) fp32
    float* out = (float*)d_out;               // (16384, 10) fp32
    const int B = in_sizes[0] / NQ;           // 16384, divisible by EPB
    vq_main<<<dim3(B / EPB), dim3(TPB), 0, stream>>>(x, w, out);
}

// Round 2
// 227.387 us; speedup vs baseline: 1.4690x; 1.4690x over previous
//
#include <hip/hip_runtime.h>
#include <math.h>

#define NQ 10
#define NL 3
#define PI_F 3.14159265358979f
#define EPB 4          // batch elements per block, one full wave (64 threads) each
#define TPB 256
#define CSLOTS 1056    // 1024 complex amps + 32 pad slots (1 per 32) per element

// Composed CNOT-ring permutation (GF(2)-linear: P(a^b)=P(a)^P(b)).
// Reference applies state = state[:, perms[i]] for i=0..9 (innermost perms[9]).
__device__ __forceinline__ int cnot_chain(int j) {
#pragma unroll
    for (int i = NQ - 1; i >= 0; --i) {
        int tq = (i + 1) % NQ;
        j ^= ((j >> (NQ - 1 - i)) & 1) << (NQ - 1 - tq);
    }
    return j;
}

// 2x2 complex gate on register-pair bit pb of the 16-amp array (compile-time pb).
#define APPLY_GATE16(pb, m0, m1)                                              \
    {                                                                         \
        _Pragma("unroll")                                                     \
        for (int j0 = 0; j0 < 16; ++j0) {                                     \
            if (((j0 >> (pb)) & 1) == 0) {                                    \
                const int j1 = j0 | (1 << (pb));                              \
                float s0r = ar[j0], s0i = ai[j0];                             \
                float s1r = ar[j1], s1i = ai[j1];                             \
                ar[j0] = m0.x * s0r - m0.y * s0i + m0.z * s1r - m0.w * s1i;   \
                ai[j0] = m0.x * s0i + m0.y * s0r + m0.z * s1i + m0.w * s1r;   \
                ar[j1] = m1.x * s0r - m1.y * s0i + m1.z * s1r - m1.w * s1i;   \
                ai[j1] = m1.x * s0i + m1.y * s0r + m1.z * s1i + m1.w * s1r;   \
            }                                                                 \
        }                                                                     \
    }

// 2x2 complex gate on lane-bit `mask` via cross-lane shuffle.
// lo lane holds s0 (uses row m0), hi lane holds s1 (uses row m1, cols swapped
// so "mine" coefficient comes first) — row/col select hoisted out of the loop.
#define SHFL_GATE(mask, m0, m1)                                               \
    {                                                                         \
        const bool hi_ = (t & (mask)) != 0;                                   \
        const float A_ = hi_ ? m1.z : m0.x;                                   \
        const float B_ = hi_ ? m1.w : m0.y;                                   \
        const float C_ = hi_ ? m1.x : m0.z;                                   \
        const float D_ = hi_ ? m1.y : m0.w;                                   \
        _Pragma("unroll")                                                     \
        for (int i2 = 0; i2 < 16; ++i2) {                                     \
            float prr = __shfl_xor(ar[i2], (mask), 64);                       \
            float pii = __shfl_xor(ai[i2], (mask), 64);                       \
            float xr = ar[i2], xi = ai[i2];                                   \
            ar[i2] = A_ * xr - B_ * xi + C_ * prr - D_ * pii;                 \
            ai[i2] = A_ * xi + B_ * xr + C_ * pii + D_ * prr;                 \
        }                                                                     \
    }

__global__ __launch_bounds__(TPB, 4) void vq_main(
        const float* __restrict__ x, const float* __restrict__ w,
        float* __restrict__ out) {
    __shared__ float2 st[EPB][CSLOTS];     // interleaved re/im state
    __shared__ float4 msh[NL * NQ * 2];    // 30 fused gate matrices

    const int tid = threadIdx.x;
    const int e = tid >> 6;        // batch sub-element (one wave each)
    const int t = tid & 63;        // lane within element
    const int b = blockIdx.x * EPB + e;

    // ---- fused M = Rz(c)*Ry(b)*Rx(a) per (layer,qubit), one thread each
    if (tid < NL * NQ) {
        const float* wp = w + tid * 3;
        float sa = __sinf(wp[0] * 0.5f), ca = __cosf(wp[0] * 0.5f);
        float sb = __sinf(wp[1] * 0.5f), cb = __cosf(wp[1] * 0.5f);
        float sc = __sinf(wp[2] * 0.5f), cc = __cosf(wp[2] * 0.5f);
        // C = Ry*Rx
        float c00r = cb * ca,  c00i =  sa * sb;
        float c01r = -sb * ca, c01i = -cb * sa;
        float c10r =  sb * ca, c10i = -cb * sa;
        float c11r =  cb * ca, c11i = -sb * sa;
        // M = Rz*C : row0 *= (cc - i sc), row1 *= (cc + i sc)
        float4 m0, m1;
        m0.x = cc * c00r + sc * c00i;  m0.y = cc * c00i - sc * c00r;
        m0.z = cc * c01r + sc * c01i;  m0.w = cc * c01i - sc * c01r;
        m1.x = cc * c10r - sc * c10i;  m1.y = cc * c10i + sc * c10r;
        m1.z = cc * c11r - sc * c11i;  m1.w = cc * c11i + sc * c11r;
        msh[tid * 2] = m0;
        msh[tid * 2 + 1] = m1;
    }

    // ---- encoding half-angles: h = tanh(x)*pi/2 (tanh via expf, range-safe)
    float cq[NQ], sq[NQ];
#pragma unroll
    for (int q = 0; q < NQ; ++q) {
        float xv = x[b * NQ + q];
        float ex = __expf(2.0f * xv);
        float th = 1.0f - 2.0f / (ex + 1.0f);
        float h = th * (PI_F * 0.5f);
        sq[q] = __sinf(h);
        cq[q] = __cosf(h);
    }

    // P(t<<4): lane bit m is k-bit 4+m (phase A: k = t*16 + j)
    int Pt = 0;
#pragma unroll
    for (int m = 0; m < 6; ++m)
        Pt ^= ((t >> m) & 1) ? cnot_chain(1 << (4 + m)) : 0;

    // per-qubit factor pair for the permuted product state
    float f0[NQ], f1[NQ];
#pragma unroll
    for (int q = 0; q < NQ; ++q) {
        bool bt = (Pt >> (9 - q)) & 1;
        f0[q] = bt ? sq[q] : cq[q];   // factor when Pj bit is 0
        f1[q] = bt ? cq[q] : sq[q];   // factor when Pj bit is 1 (flipped)
    }

    // ---- layer-0 phase A: product amplitudes at P(k), perm fused (all real)
    float ar[16], ai[16];
#pragma unroll
    for (int j = 0; j < 16; ++j) {
        const int pj = cnot_chain(j);   // compile-time constant
        float r = 1.0f;
#pragma unroll
        for (int q = 0; q < NQ; ++q)
            r *= ((pj >> (9 - q)) & 1) ? f1[q] : f0[q];
        ar[j] = r;
        ai[j] = 0.0f;
    }

    __syncthreads();   // msh ready

#pragma unroll 1
    for (int l = 0; l < NL; ++l) {
        if (l > 0) {
            // phase-A gather with CNOT-ring perm fused: s_new(k) = s_old(P(k))
#pragma unroll
            for (int j = 0; j < 16; ++j) {
                const int pj = cnot_chain(j);
                int pk = Pt ^ pj;
                float2 v = st[e][pk + (pk >> 5)];
                ar[j] = v.x;
                ai[j] = v.y;
            }
            __syncthreads();   // all gathers done before phase-A overwrites
        }
        __builtin_amdgcn_sched_barrier(0);   // keep matrix loads in-phase
        // phase A: qubits 6..9 live in j bits 3..0
#pragma unroll
        for (int q = 6; q < NQ; ++q) {
            float4 m0 = msh[(l * NQ + q) * 2];
            float4 m1 = msh[(l * NQ + q) * 2 + 1];
            APPLY_GATE16(9 - q, m0, m1);
        }
        // qubits 4,5 live in lane bits 1,0 (k bits 5,4) — shuffle gates
        {
            float4 m0 = msh[(l * NQ + 4) * 2], m1 = msh[(l * NQ + 4) * 2 + 1];
            SHFL_GATE(2, m0, m1);
        }
        {
            float4 m0 = msh[(l * NQ + 5) * 2], m1 = msh[(l * NQ + 5) * 2 + 1];
            SHFL_GATE(1, m0, m1);
        }
        // write canonical slots: k = t*16 + j, slot = k + (k>>5) = t*16+(t>>1)+j
        {
            const int base = t * 16 + (t >> 1);
#pragma unroll
            for (int j = 0; j < 16; ++j)
                st[e][base + j] = make_float2(ar[j], ai[j]);
        }
        __syncthreads();
        __builtin_amdgcn_sched_barrier(0);
        // phase B read: amp i holds k = i*64 + t, slot = i*66 + t + (t>>5)
        {
            const int boff = t + (t >> 5);
#pragma unroll
            for (int i = 0; i < 16; ++i) {
                float2 v = st[e][i * 66 + boff];
                ar[i] = v.x;
                ai[i] = v.y;
            }
        }
        // phase B: qubits 0..3 live in i bits 3..0
#pragma unroll
        for (int q = 0; q < 4; ++q) {
            float4 m0 = msh[(l * NQ + q) * 2];
            float4 m1 = msh[(l * NQ + q) * 2 + 1];
            APPLY_GATE16(3 - q, m0, m1);
        }
        if (l < NL - 1) {
            // same slots this thread just read -> no barrier before writes
            const int boff = t + (t >> 5);
#pragma unroll
            for (int i = 0; i < 16; ++i)
                st[e][i * 66 + boff] = make_float2(ar[i], ai[i]);
            __syncthreads();
        }
    }

    // ---- readout from phase-B registers: k = i*64 + t
    // qubits 0..3 from i bits, qubits 4..9 from t bits
    float S = 0.0f;
    float accw[NQ];
#pragma unroll
    for (int wi = 0; wi < 4; ++wi) accw[wi] = 0.0f;
#pragma unroll
    for (int i = 0; i < 16; ++i) {
        float p = ar[i] * ar[i] + ai[i] * ai[i];
        S += p;
#pragma unroll
        for (int wi = 0; wi < 4; ++wi)
            accw[wi] += ((i >> (3 - wi)) & 1) ? -p : p;
    }
#pragma unroll
    for (int wi = 4; wi < NQ; ++wi)
        accw[wi] = ((t >> (9 - wi)) & 1) ? -S : S;

    // full-wave reduction (64 lanes = one batch element)
#pragma unroll
    for (int wi = 0; wi < NQ; ++wi) {
        float v = accw[wi];
        v += __shfl_xor(v, 1, 64);
        v += __shfl_xor(v, 2, 64);
        v += __shfl_xor(v, 4, 64);
        v += __shfl_xor(v, 8, 64);
        v += __shfl_xor(v, 16, 64);
        v += __shfl_xor(v, 32, 64);
        accw[wi] = v;
    }
    if (t == 0) {
#pragma unroll
        for (int wi = 0; wi < NQ; ++wi)
            out[b * NQ + wi] = accw[wi];
    }
}

extern "C" void kernel_launch(void* const* d_in, const int* in_sizes, int n_in,
                              void* d_out, int out_size, void* d_ws, size_t ws_size,
                              hipStream_t stream) {
    const float* x = (const float*)d_in[0];   // (16384, 10) fp32
    const float* w = (const float*)d_in[1];   // (3, 10, 3) fp32
    float* out = (float*)d_out;               // (16384, 10) fp32
    const int B = in_sizes[0] / NQ;           // 16384
    vq_main<<<dim3(B / EPB), dim3(TPB), 0, stream>>>(x, w, out);
}

// Round 3
// 225.419 us; speedup vs baseline: 1.4818x; 1.0087x over previous
//
#include <hip/hip_runtime.h>
#include <math.h>

#define NQ 10
#define NL 3
#define PI_F 3.14159265358979f
#define EPB 4          // batch elements per block, one full wave (64 threads) each
#define TPB 256
#define CSLOTS 1056    // 1024 complex amps + 32 pad slots (1 per 32) per element

// Composed CNOT-ring permutation (GF(2)-linear: P(a^b)=P(a)^P(b)).
// Reference applies state = state[:, perms[i]] for i=0..9 (innermost perms[9]).
__device__ __forceinline__ int cnot_chain(int j) {
#pragma unroll
    for (int i = NQ - 1; i >= 0; --i) {
        int tq = (i + 1) % NQ;
        j ^= ((j >> (NQ - 1 - i)) & 1) << (NQ - 1 - tq);
    }
    return j;
}

// 2x2 complex gate on register-pair bit pb of the 16-amp array (compile-time pb).
#define APPLY_GATE16(pb, m0, m1)                                              \
    {                                                                         \
        _Pragma("unroll")                                                     \
        for (int j0 = 0; j0 < 16; ++j0) {                                     \
            if (((j0 >> (pb)) & 1) == 0) {                                    \
                const int j1 = j0 | (1 << (pb));                              \
                float s0r = ar[j0], s0i = ai[j0];                             \
                float s1r = ar[j1], s1i = ai[j1];                             \
                ar[j0] = m0.x * s0r - m0.y * s0i + m0.z * s1r - m0.w * s1i;   \
                ai[j0] = m0.x * s0i + m0.y * s0r + m0.z * s1i + m0.w * s1r;   \
                ar[j1] = m1.x * s0r - m1.y * s0i + m1.z * s1r - m1.w * s1i;   \
                ai[j1] = m1.x * s0i + m1.y * s0r + m1.z * s1i + m1.w * s1r;   \
            }                                                                 \
        }                                                                     \
    }

// 2x2 complex gate on lane-bit `mask` via cross-lane shuffle (DPP for mask 1/2).
#define SHFL_GATE(mask, m0, m1)                                               \
    {                                                                         \
        const bool hi_ = (t & (mask)) != 0;                                   \
        const float A_ = hi_ ? m1.z : m0.x;                                   \
        const float B_ = hi_ ? m1.w : m0.y;                                   \
        const float C_ = hi_ ? m1.x : m0.z;                                   \
        const float D_ = hi_ ? m1.y : m0.w;                                   \
        _Pragma("unroll")                                                     \
        for (int i2 = 0; i2 < 16; ++i2) {                                     \
            float prr = __shfl_xor(ar[i2], (mask), 64);                       \
            float pii = __shfl_xor(ai[i2], (mask), 64);                       \
            float xr = ar[i2], xi = ai[i2];                                   \
            ar[i2] = A_ * xr - B_ * xi + C_ * prr - D_ * pii;                 \
            ai[i2] = A_ * xi + B_ * xr + C_ * pii + D_ * prr;                 \
        }                                                                     \
    }

__global__ __launch_bounds__(TPB)
__attribute__((amdgpu_waves_per_eu(4, 4)))   // pin alloc: 128 VGPRs, no 8-wave chase
void vq_main(const float* __restrict__ x, const float* __restrict__ w,
             float* __restrict__ out) {
    __shared__ float2 st[EPB][CSLOTS];     // interleaved re/im state
    __shared__ float4 msh[NL * NQ * 2];    // 30 fused gate matrices

    const int tid = threadIdx.x;
    const int e = tid >> 6;        // batch sub-element (one wave each)
    const int t = tid & 63;        // lane within element
    const int b = blockIdx.x * EPB + e;

    // ---- fused M = Rz(c)*Ry(b)*Rx(a) per (layer,qubit), one thread each
    if (tid < NL * NQ) {
        const float* wp = w + tid * 3;
        float sa = __sinf(wp[0] * 0.5f), ca = __cosf(wp[0] * 0.5f);
        float sb = __sinf(wp[1] * 0.5f), cb = __cosf(wp[1] * 0.5f);
        float sc = __sinf(wp[2] * 0.5f), cc = __cosf(wp[2] * 0.5f);
        // C = Ry*Rx
        float c00r = cb * ca,  c00i =  sa * sb;
        float c01r = -sb * ca, c01i = -cb * sa;
        float c10r =  sb * ca, c10i = -cb * sa;
        float c11r =  cb * ca, c11i = -sb * sa;
        // M = Rz*C : row0 *= (cc - i sc), row1 *= (cc + i sc)
        float4 m0, m1;
        m0.x = cc * c00r + sc * c00i;  m0.y = cc * c00i - sc * c00r;
        m0.z = cc * c01r + sc * c01i;  m0.w = cc * c01i - sc * c01r;
        m1.x = cc * c10r - sc * c10i;  m1.y = cc * c10i + sc * c10r;
        m1.z = cc * c11r - sc * c11i;  m1.w = cc * c11i + sc * c11r;
        msh[tid * 2] = m0;
        msh[tid * 2 + 1] = m1;
    }

    // P(t<<4): lane bit m is k-bit 4+m (phase A: k = t*16 + j)
    int Pt = 0;
#pragma unroll
    for (int m = 0; m < 6; ++m)
        Pt ^= ((t >> m) & 1) ? cnot_chain(1 << (4 + m)) : 0;

    // ---- encoding: h = tanh(x)*pi/2; fold Pt-bit selection directly into
    // the per-qubit factor pair (no separate cq/sq arrays -> lower pressure)
    float f0[NQ], f1[NQ];
#pragma unroll
    for (int q = 0; q < NQ; ++q) {
        float xv = x[b * NQ + q];
        float ex = __expf(2.0f * xv);
        float th = 1.0f - 2.0f / (ex + 1.0f);
        float h = th * (PI_F * 0.5f);
        float s = __sinf(h), c = __cosf(h);
        bool bt = (Pt >> (9 - q)) & 1;
        f0[q] = bt ? s : c;   // factor when Pj bit is 0
        f1[q] = bt ? c : s;   // factor when Pj bit is 1 (flipped)
    }

    // ---- layer-0 phase A: product amplitudes at P(k), perm fused (all real)
    float ar[16], ai[16];
#pragma unroll
    for (int j = 0; j < 16; ++j) {
        const int pj = cnot_chain(j);   // compile-time constant
        float r = 1.0f;
#pragma unroll
        for (int q = 0; q < NQ; ++q)
            r *= ((pj >> (9 - q)) & 1) ? f1[q] : f0[q];
        ar[j] = r;
        ai[j] = 0.0f;
    }

    __syncthreads();   // msh ready

#pragma unroll 1
    for (int l = 0; l < NL; ++l) {
        if (l > 0) {
            // phase-A gather with CNOT-ring perm fused: s_new(k) = s_old(P(k))
#pragma unroll
            for (int j = 0; j < 16; ++j) {
                const int pj = cnot_chain(j);
                int pk = Pt ^ pj;
                float2 v = st[e][pk + (pk >> 5)];
                ar[j] = v.x;
                ai[j] = v.y;
            }
            __syncthreads();   // all gathers done before phase-A overwrites
        }
        __builtin_amdgcn_sched_barrier(0);   // keep matrix loads in-phase
        // phase A: qubits 6..9 live in j bits 3..0
#pragma unroll
        for (int q = 6; q < NQ; ++q) {
            float4 m0 = msh[(l * NQ + q) * 2];
            float4 m1 = msh[(l * NQ + q) * 2 + 1];
            APPLY_GATE16(9 - q, m0, m1);
        }
        // qubits 4,5 live in lane bits 1,0 (k bits 5,4) — shuffle gates
        {
            float4 m0 = msh[(l * NQ + 4) * 2], m1 = msh[(l * NQ + 4) * 2 + 1];
            SHFL_GATE(2, m0, m1);
        }
        {
            float4 m0 = msh[(l * NQ + 5) * 2], m1 = msh[(l * NQ + 5) * 2 + 1];
            SHFL_GATE(1, m0, m1);
        }
        // write canonical slots: k = t*16 + j, slot = k + (k>>5) = t*16+(t>>1)+j
        {
            const int base = t * 16 + (t >> 1);
#pragma unroll
            for (int j = 0; j < 16; ++j)
                st[e][base + j] = make_float2(ar[j], ai[j]);
        }
        __syncthreads();
        __builtin_amdgcn_sched_barrier(0);
        // phase B read: amp i holds k = i*64 + t, slot = i*66 + t + (t>>5)
        {
            const int boff = t + (t >> 5);
#pragma unroll
            for (int i = 0; i < 16; ++i) {
                float2 v = st[e][i * 66 + boff];
                ar[i] = v.x;
                ai[i] = v.y;
            }
        }
        // phase B: qubits 0..3 live in i bits 3..0
#pragma unroll
        for (int q = 0; q < 4; ++q) {
            float4 m0 = msh[(l * NQ + q) * 2];
            float4 m1 = msh[(l * NQ + q) * 2 + 1];
            APPLY_GATE16(3 - q, m0, m1);
        }
        if (l < NL - 1) {
            // same slots this thread just read -> no barrier before writes
            const int boff = t + (t >> 5);
#pragma unroll
            for (int i = 0; i < 16; ++i)
                st[e][i * 66 + boff] = make_float2(ar[i], ai[i]);
            __syncthreads();
        }
    }

    // ---- readout from phase-B registers: k = i*64 + t
    // qubits 0..3 from i bits, qubits 4..9 from t bits
    float S = 0.0f;
    float accw[NQ];
#pragma unroll
    for (int wi = 0; wi < 4; ++wi) accw[wi] = 0.0f;
#pragma unroll
    for (int i = 0; i < 16; ++i) {
        float p = ar[i] * ar[i] + ai[i] * ai[i];
        S += p;
#pragma unroll
        for (int wi = 0; wi < 4; ++wi)
            accw[wi] += ((i >> (3 - wi)) & 1) ? -p : p;
    }
#pragma unroll
    for (int wi = 4; wi < NQ; ++wi)
        accw[wi] = ((t >> (9 - wi)) & 1) ? -S : S;

    // full-wave reduction (64 lanes = one batch element)
#pragma unroll
    for (int wi = 0; wi < NQ; ++wi) {
        float v = accw[wi];
        v += __shfl_xor(v, 1, 64);
        v += __shfl_xor(v, 2, 64);
        v += __shfl_xor(v, 4, 64);
        v += __shfl_xor(v, 8, 64);
        v += __shfl_xor(v, 16, 64);
        v += __shfl_xor(v, 32, 64);
        accw[wi] = v;
    }
    if (t == 0) {
#pragma unroll
        for (int wi = 0; wi < NQ; ++wi)
            out[b * NQ + wi] = accw[wi];
    }
}

extern "C" void kernel_launch(void* const* d_in, const int* in_sizes, int n_in,
                              void* d_out, int out_size, void* d_ws, size_t ws_size,
                              hipStream_t stream) {
    const float* x = (const float*)d_in[0];   // (16384, 10) fp32
    const float* w = (const float*)d_in[1];   // (3, 10, 3) fp32
    float* out = (float*)d_out;               // (16384, 10) fp32
    const int B = in_sizes[0] / NQ;           // 16384
    vq_main<<<dim3(B / EPB), dim3(TPB), 0, stream>>>(x, w, out);
}